// Round 8
// baseline (821.938 us; speedup 1.0000x reference)
//
#include <hip/hip_runtime.h>
#include <stdint.h>
#include <math.h>

// Problem dims
#define T_ 4
#define B_ 8
#define C_ 256
#define N_ 2048
#define TB_ 32          // T_*B_
#define H_ 16
#define D_ 16
#define NTOT 65536      // T_*B_*N_  (BN reduction count per channel)
#define EPS 1e-5
#define NSLOT 1024      // per-channel partial-stat slots = n_blocks(32) * tb(32)
#define WPSZ 327680     // 16 cchunk * 256 o * 5 limb * 16 B

typedef int v4i __attribute__((ext_vector_type(4)));

// ---------------------------------------------------------------------------
// W prep: decompose fp32 256x256 matrices into 5 balanced i8 limbs @2^40 and
// store in the conv's A-fragment-friendly permuted layout:
//   WP[cchunk(16)][o(256)][limb(5)][16 bytes]   (cchunk = c>>4, byte = c&15)
// Lane A-load: 16 contiguous bytes per (o,cchunk,limb). Exact: |w|<0.5.
// ---------------------------------------------------------------------------
__global__ __launch_bounds__(256) void wprep_kernel(const float* __restrict__ W0,
                                                    const float* __restrict__ W1,
                                                    const float* __restrict__ W2,
                                                    int8_t* __restrict__ out) {
  const float* Wm = (blockIdx.y == 0) ? W0 : ((blockIdx.y == 1) ? W1 : W2);
  const int o = blockIdx.x;
  const int c = (int)threadIdx.x;
  double rr = rint((double)Wm[o * C_ + c] * 0x1p40);
  int8_t* base = out + (size_t)blockIdx.y * WPSZ + (size_t)(c >> 4) * 20480 +
                 (size_t)o * 80 + (c & 15);
#pragma unroll
  for (int L = 0; L < 5; ++L) {
    const double q = floor(fma(rr, 0.00390625, 0.5));
    const double d = fma(q, -256.0, rr);
    base[L * 16] = (int8_t)(int)d;
    rr = q;
  }
}

// ---------------------------------------------------------------------------
// X prep: extract 4 balanced i8 limbs @2^28 per element (int chain, verified
// round 7) and store packed in the conv's B-fragment layout:
//   XP[tb][cchunk(16)][n(2048)][limb(4)][16 bytes]
// Writes are 64 B contiguous per thread, consecutive threads consecutive n ->
// fully coalesced. Grid (N/64, TB), block 256.
// ---------------------------------------------------------------------------
__global__ __launch_bounds__(256) void xprep_kernel(const float* __restrict__ X,
                                                    uint8_t* __restrict__ XP) {
  __shared__ float Xs[64][81];
  const int n0 = blockIdx.x * 64;
  const int tb = blockIdx.y;
  const int tid = (int)threadIdx.x;
  const int c_l = tid >> 2, nc = tid & 3;   // staging: c row, n-chunk
  const int n_l = tid & 63, cq = tid >> 6;  // extraction: n, c-quarter

  const float* Xp = X + ((size_t)(tb * C_ + c_l)) * N_ + n0 + nc * 16;

  for (int slab = 0; slab < 4; ++slab) {
    __syncthreads();
#pragma unroll
    for (int r = 0; r < 4; ++r) {
      const float4 xv = *(const float4*)(Xp + (size_t)(slab * 64) * N_ + 4 * r);
      Xs[c_l][nc * 16 + 4 * r + 0] = xv.x;
      Xs[c_l][nc * 16 + 4 * r + 1] = xv.y;
      Xs[c_l][nc * 16 + 4 * r + 2] = xv.z;
      Xs[c_l][nc * 16 + 4 * r + 3] = xv.w;
    }
    __syncthreads();
    uint32_t pk[4][4] = {};
#pragma unroll
    for (int s = 0; s < 16; ++s) {
      const float f = Xs[cq * 16 + s][n_l];
      union { double d; unsigned long long u; } cv;
      cv.d = fma((double)f, 0x1p28, 0x1.8p52);  // RNE round; low dword = int32
      int v = (int)(uint32_t)(cv.u & 0xffffffffULL);
      const int d0 = (int)(int8_t)v;  v = (v - d0) >> 8;
      const int d1 = (int)(int8_t)v;  v = (v - d1) >> 8;
      const int d2 = (int)(int8_t)v;
      const int d3 = (v - d2) >> 8;
      const int sh = 8 * (s & 3);
      const int w = s >> 2;
      pk[0][w] |= (uint32_t)(d0 & 255) << sh;
      pk[1][w] |= (uint32_t)(d1 & 255) << sh;
      pk[2][w] |= (uint32_t)(d2 & 255) << sh;
      pk[3][w] |= (uint32_t)(d3 & 255) << sh;
    }
    uint8_t* dst =
        XP + (((size_t)(tb * 16 + slab * 4 + cq)) * (size_t)N_ + n0 + n_l) * 64;
#pragma unroll
    for (int j = 0; j < 4; ++j) {
      const int4 wv = make_int4((int)pk[j][0], (int)pk[j][1], (int)pk[j][2], (int)pk[j][3]);
      *(int4*)(dst + 16 * j) = wv;
    }
  }
}

// ---------------------------------------------------------------------------
// Barrier-free i8 GEMM conv, two epilogue modes.
//   QKV=true : B = XP 4-limb layout; 14 MFMAs/mt (i+j>=3), bucket a=i+j-3,
//              h = sum_a acc_a * 2^(8a-44)  (round-7-verified algebra).
//   QKV=false: B = SbufT binary (exact single limb); 5 MFMAs/mt (bucket i),
//              h = sum_i acc_i * 2^(8i-40).
//   STATS=true : epilogue writes per-channel (sum,sumsq) partials.
//   STATS=false: epilogue applies BN+spike: a_c*h + b_c >= 1 -> OutT {0,1}.
// Block 256 (4 waves = 4 n-subtiles), tile 64o x 64n, K in 4 slabs of 64.
// No __syncthreads in the K-loop: A from L2-hot WP, B coalesced from global.
// D layout: col=lane&15 (=n), row=4*(lane>>4)+reg [HW-verified m121-128].
// ---------------------------------------------------------------------------
template <bool QKV, bool STATS, typename OutT>
__global__ __launch_bounds__(256) void conv_i8(
    const int8_t* __restrict__ WP, const uint8_t* __restrict__ BP,
    double* __restrict__ Psum, double* __restrict__ Psq,
    const float* __restrict__ gamma, const float* __restrict__ beta,
    const double* __restrict__ mean, const double* __restrict__ invstd,
    OutT* __restrict__ Out) {
  __shared__ double dsum[4][64];
  __shared__ double dsq[4][64];
  __shared__ double aS[64];
  __shared__ double bS[64];
  const int n0 = blockIdx.x * 64;
  const int o0 = blockIdx.y * 64;
  const int tb = blockIdx.z;
  const int tid = (int)threadIdx.x;
  const int wv = tid >> 6;
  const int lane = tid & 63;
  const int l15 = lane & 15;
  const int g = lane >> 4;
  const int nn = 16 * wv + l15;

  if constexpr (!STATS) {
    if (tid < 64) {
      const int c = o0 + tid;
      const double is = invstd[c], mu = mean[c];
      const double gm = (double)gamma[c], bt = (double)beta[c];
      aS[tid] = gm * is;
      bS[tid] = bt - gm * mu * is;
    }
    __syncthreads();
  }

  v4i acc[4][5] = {};

  for (int slab = 0; slab < 4; ++slab) {
    const int cc = slab * 4 + g;
    v4i Bf[4];
    if constexpr (QKV) {
      const uint8_t* bp = BP + (((size_t)(tb * 16 + cc)) * (size_t)N_ + n0 + nn) * 64;
#pragma unroll
      for (int j = 0; j < 4; ++j) Bf[j] = *(const v4i*)(bp + 16 * j);
    } else {
      Bf[0] = *(const v4i*)(BP + ((size_t)(tb * N_ + n0 + nn)) * 256 + slab * 64 + 16 * g);
    }
#pragma unroll
    for (int mt = 0; mt < 4; ++mt) {
      const int8_t* ap = WP + (size_t)cc * 20480 + (size_t)(o0 + 16 * mt + l15) * 80;
      v4i A[5];
#pragma unroll
      for (int i = 0; i < 5; ++i) A[i] = *(const v4i*)(ap + 16 * i);
      if constexpr (QKV) {
        // bucket round-robin order: same-bucket spacing >= 4
        constexpr int PI[14] = {0, 1, 2, 3, 4, 1, 2, 3, 4, 2, 3, 4, 3, 4};
        constexpr int PJ[14] = {3, 3, 3, 3, 3, 2, 2, 2, 2, 1, 1, 1, 0, 0};
#pragma unroll
        for (int p = 0; p < 14; ++p)
          acc[mt][PI[p] + PJ[p] - 3] = __builtin_amdgcn_mfma_i32_16x16x64_i8(
              A[PI[p]], Bf[PJ[p]], acc[mt][PI[p] + PJ[p] - 3], 0, 0, 0);
      } else {
#pragma unroll
        for (int i = 0; i < 5; ++i)
          acc[mt][i] = __builtin_amdgcn_mfma_i32_16x16x64_i8(A[i], Bf[0], acc[mt][i], 0, 0, 0);
      }
    }
  }

  const double scale[5] = {QKV ? 0x1p-44 : 0x1p-40, QKV ? 0x1p-36 : 0x1p-32,
                           QKV ? 0x1p-28 : 0x1p-24, QKV ? 0x1p-20 : 0x1p-16,
                           QKV ? 0x1p-12 : 0x1p-8};

  if constexpr (STATS) {
#pragma unroll
    for (int mt = 0; mt < 4; ++mt) {
      double s[4], q[4];
#pragma unroll
      for (int r = 0; r < 4; ++r) {
        double v = 0.0;
#pragma unroll
        for (int a = 0; a < 5; ++a) v = fma(scale[a], (double)acc[mt][a][r], v);
        s[r] = v;
        q[r] = v * v;
      }
#pragma unroll
      for (int m = 1; m < 16; m <<= 1) {
#pragma unroll
        for (int r = 0; r < 4; ++r) {
          s[r] += __shfl_xor(s[r], m);
          q[r] += __shfl_xor(q[r], m);
        }
      }
      if (l15 < 4) {
        dsum[wv][16 * mt + 4 * g + l15] = s[l15];
        dsq[wv][16 * mt + 4 * g + l15] = q[l15];
      }
    }
    __syncthreads();
    if (tid < 64) {
      const double S = dsum[0][tid] + dsum[1][tid] + dsum[2][tid] + dsum[3][tid];
      const double Q = dsq[0][tid] + dsq[1][tid] + dsq[2][tid] + dsq[3][tid];
      const int slot = tb * 32 + (int)blockIdx.x;
      Psum[(size_t)(o0 + tid) * NSLOT + slot] = S;
      Psq[(size_t)(o0 + tid) * NSLOT + slot] = Q;
    }
  } else {
#pragma unroll
    for (int mt = 0; mt < 4; ++mt) {
#pragma unroll
      for (int r = 0; r < 4; ++r) {
        double v = 0.0;
#pragma unroll
        for (int a = 0; a < 5; ++a) v = fma(scale[a], (double)acc[mt][a][r], v);
        const int row = 16 * mt + 4 * g + r;
        const int sp = (aS[row] * v + bS[row] >= 1.0) ? 1 : 0;
        Out[((size_t)(tb * C_ + o0 + row)) * N_ + n0 + nn] = (OutT)sp;
      }
    }
  }
}

// ---------------------------------------------------------------------------
// Finalize BN stats: one block per channel, reduce NSLOT partials (fp64).
// ---------------------------------------------------------------------------
__global__ __launch_bounds__(256) void finalize_stats(const double* __restrict__ Psum,
                                                      const double* __restrict__ Psq,
                                                      double* __restrict__ mean,
                                                      double* __restrict__ invstd) {
  const int c = blockIdx.x;
  const int tid = (int)threadIdx.x;
  double s = 0.0, q = 0.0;
  for (int i = tid; i < NSLOT; i += 256) {
    s += Psum[(size_t)c * NSLOT + i];
    q += Psq[(size_t)c * NSLOT + i];
  }
#pragma unroll
  for (int m = 1; m < 64; m <<= 1) {
    s += __shfl_xor(s, m);
    q += __shfl_xor(q, m);
  }
  __shared__ double ls[4], lq[4];
  if ((tid & 63) == 0) {
    ls[tid >> 6] = s;
    lq[tid >> 6] = q;
  }
  __syncthreads();
  if (tid == 0) {
    const double S = ls[0] + ls[1] + ls[2] + ls[3];
    const double Q = lq[0] + lq[1] + lq[2] + lq[3];
    const double m = S / (double)NTOT;
    const double var = Q / (double)NTOT - m * m;
    mean[c] = m;
    invstd[c] = 1.0 / sqrt(var + EPS);
  }
}

// ---------------------------------------------------------------------------
// Linear attention (exact integer path). Output written TRANSPOSED:
//   SbufT[tb][n][c] (c contiguous) -> proj's B-fragments are direct 16B loads.
// Each thread at position n holds all 16 e-values of its head -> one int4.
// ---------------------------------------------------------------------------
__global__ __launch_bounds__(256) void attn_kernel(const uint8_t* __restrict__ Sq,
                                                   const uint8_t* __restrict__ Sk,
                                                   const uint8_t* __restrict__ Sv,
                                                   uint8_t* __restrict__ SbufT) {
  __shared__ float kvs[16][17];
  const int tb = (int)blockIdx.x >> 4;
  const int h = (int)blockIdx.x & 15;
  const size_t base = ((size_t)(tb * C_ + h * D_)) * N_;
  const int tid = (int)threadIdx.x;
  {
    const int d = tid >> 4, e = tid & 15;
    const uint32_t* kr = (const uint32_t*)(Sk + base + (size_t)d * N_);
    const uint32_t* vr = (const uint32_t*)(Sv + base + (size_t)e * N_);
    int cnt = 0;
    for (int i = 0; i < N_ / 4; ++i) cnt += __popc(kr[i] & vr[i]);
    kvs[d][e] = (float)cnt;
  }
  __syncthreads();
  for (int rep = 0; rep < 8; ++rep) {
    const int n = rep * 256 + tid;
    float qv[16];
#pragma unroll
    for (int d = 0; d < 16; ++d) qv[d] = (float)Sq[base + (size_t)d * N_ + n];
    uint32_t w[4] = {0, 0, 0, 0};
#pragma unroll
    for (int e = 0; e < 16; ++e) {
      float acc = 0.f;
#pragma unroll
      for (int d = 0; d < 16; ++d) acc += qv[d] * kvs[d][e];
      const uint32_t sp = (0.25f * acc >= 0.5f) ? 1u : 0u;
      w[e >> 2] |= sp << (8 * (e & 3));
    }
    const int4 pw = make_int4((int)w[0], (int)w[1], (int)w[2], (int)w[3]);
    *(int4*)(SbufT + ((size_t)(tb * N_ + n)) * 256 + h * 16) = pw;
  }
}

// ---------------------------------------------------------------------------
// Launcher. ws layout (max offset 192 MB, proven; h64 is GONE):
//   [0,   64M)  XPx  (x limbs, packed B layout)
//   [64M,128M)  XPy  (y limbs)
//   [128M,144M) Sq   [144M,160M) Sk   [160M,176M) Sv   [176M,192M) SbufT
// Overlays in dead regions:
//   statsA (4M) at SbufT+0, WPA (3x320K) at SbufT+5M  (dead until attn)
//   statsB (4M) at Sq+0,    WPB (320K)   at Sq+8M     (Sq dead after attn)
// ---------------------------------------------------------------------------
extern "C" void kernel_launch(void* const* d_in, const int* in_sizes, int n_in,
                              void* d_out, int out_size, void* d_ws, size_t ws_size,
                              hipStream_t stream) {
  const float* x   = (const float*)d_in[0];
  const float* y   = (const float*)d_in[1];
  const float* q_w = (const float*)d_in[2];
  const float* q_g = (const float*)d_in[3];
  const float* q_b = (const float*)d_in[4];
  const float* k_w = (const float*)d_in[5];
  const float* k_g = (const float*)d_in[6];
  const float* k_b = (const float*)d_in[7];
  const float* v_w = (const float*)d_in[8];
  const float* v_g = (const float*)d_in[9];
  const float* v_b = (const float*)d_in[10];
  const float* p_w = (const float*)d_in[11];
  const float* p_g = (const float*)d_in[12];
  const float* p_b = (const float*)d_in[13];
  float* out = (float*)d_out;

  char* ws = (char*)d_ws;
  const size_t NE = (size_t)TB_ * C_ * N_;  // 16,777,216
  uint8_t* XPx   = (uint8_t*)ws;
  uint8_t* XPy   = (uint8_t*)(ws + NE * 4);
  uint8_t* Sq    = (uint8_t*)(ws + NE * 8);
  uint8_t* Sk    = Sq + NE;
  uint8_t* Sv    = Sk + NE;
  uint8_t* SbufT = Sv + NE;

  // statsA + q/k/v W planes overlaid in SbufT region (dead until attn)
  double* PsumA   = (double*)SbufT;
  double* PsqA    = PsumA + (size_t)C_ * NSLOT;
  double* meanA   = PsqA + (size_t)C_ * NSLOT;
  double* invstdA = meanA + C_;
  int8_t* WPA     = (int8_t*)(SbufT + 5 * 1024 * 1024);
  int8_t* WPq     = WPA;
  int8_t* WPk     = WPA + WPSZ;
  int8_t* WPv     = WPA + 2 * WPSZ;
  // statsB + proj W plane overlaid in Sq region (dead after attn)
  double* PsumB   = (double*)Sq;
  double* PsqB    = PsumB + (size_t)C_ * NSLOT;
  double* meanB   = PsqB + (size_t)C_ * NSLOT;
  double* invstdB = meanB + C_;
  int8_t* WPB     = (int8_t*)(Sq + 8 * 1024 * 1024);

  const dim3 gridG(N_ / 64, C_ / 64, TB_);  // 32,4,32
  const dim3 blk(256);

  // --- prep ---
  wprep_kernel<<<dim3(C_, 3), blk, 0, stream>>>(q_w, k_w, v_w, WPA);
  xprep_kernel<<<dim3(N_ / 64, TB_), blk, 0, stream>>>(x, XPx);
  xprep_kernel<<<dim3(N_ / 64, TB_), blk, 0, stream>>>(y, XPy);
  // --- Q from x ---
  conv_i8<true, true, uint8_t><<<gridG, blk, 0, stream>>>(
      WPq, XPx, PsumA, PsqA, nullptr, nullptr, nullptr, nullptr, (uint8_t*)nullptr);
  finalize_stats<<<C_, blk, 0, stream>>>(PsumA, PsqA, meanA, invstdA);
  conv_i8<true, false, uint8_t><<<gridG, blk, 0, stream>>>(
      WPq, XPx, nullptr, nullptr, q_g, q_b, meanA, invstdA, Sq);
  // --- K from y ---
  conv_i8<true, true, uint8_t><<<gridG, blk, 0, stream>>>(
      WPk, XPy, PsumA, PsqA, nullptr, nullptr, nullptr, nullptr, (uint8_t*)nullptr);
  finalize_stats<<<C_, blk, 0, stream>>>(PsumA, PsqA, meanA, invstdA);
  conv_i8<true, false, uint8_t><<<gridG, blk, 0, stream>>>(
      WPk, XPy, nullptr, nullptr, k_g, k_b, meanA, invstdA, Sk);
  // --- V from y ---
  conv_i8<true, true, uint8_t><<<gridG, blk, 0, stream>>>(
      WPv, XPy, PsumA, PsqA, nullptr, nullptr, nullptr, nullptr, (uint8_t*)nullptr);
  finalize_stats<<<C_, blk, 0, stream>>>(PsumA, PsqA, meanA, invstdA);
  conv_i8<true, false, uint8_t><<<gridG, blk, 0, stream>>>(
      WPv, XPy, nullptr, nullptr, v_g, v_b, meanA, invstdA, Sv);
  // --- attention (overwrites SbufT region incl. statsA/WPA = fine) ---
  attn_kernel<<<TB_ * H_, blk, 0, stream>>>(Sq, Sk, Sv, SbufT);
  // --- proj (overlays in Sq region, dead after attn) ---
  wprep_kernel<<<dim3(C_, 1), blk, 0, stream>>>(p_w, p_w, p_w, WPB);
  conv_i8<false, true, float><<<gridG, blk, 0, stream>>>(
      WPB, SbufT, PsumB, PsqB, nullptr, nullptr, nullptr, nullptr, (float*)nullptr);
  finalize_stats<<<C_, blk, 0, stream>>>(PsumB, PsqB, meanB, invstdB);
  conv_i8<false, false, float><<<gridG, blk, 0, stream>>>(
      WPB, SbufT, nullptr, nullptr, p_g, p_b, meanB, invstdB, out);
}

// Round 9
// 677.156 us; speedup vs baseline: 1.2138x; 1.2138x over previous
//
#include <hip/hip_runtime.h>
#include <stdint.h>
#include <math.h>

// Problem dims
#define T_ 4
#define B_ 8
#define C_ 256
#define N_ 2048
#define TB_ 32          // T_*B_
#define H_ 16
#define D_ 16
#define NTOT 65536      // T_*B_*N_  (BN reduction count per channel)
#define EPS 1e-5
#define NSLOT 1024      // per-channel partial-stat slots = n_blocks(32) * tb(32)
#define WPSZ 327680     // 16 cchunk * 256 o * 5 limb * 16 B
#define MB (1024 * 1024)

typedef int v4i __attribute__((ext_vector_type(4)));

// ---------------------------------------------------------------------------
// W prep: 5 balanced i8 limbs @2^40 in A-fragment layout
//   WP[cchunk(16)][o(256)][limb(5)][16 bytes]
// ---------------------------------------------------------------------------
__global__ __launch_bounds__(256) void wprep_kernel(const float* __restrict__ W0,
                                                    const float* __restrict__ W1,
                                                    const float* __restrict__ W2,
                                                    int8_t* __restrict__ out) {
  const float* Wm = (blockIdx.y == 0) ? W0 : ((blockIdx.y == 1) ? W1 : W2);
  const int o = blockIdx.x;
  const int c = (int)threadIdx.x;
  double rr = rint((double)Wm[o * C_ + c] * 0x1p40);
  int8_t* base = out + (size_t)blockIdx.y * WPSZ + (size_t)(c >> 4) * 20480 +
                 (size_t)o * 80 + (c & 15);
#pragma unroll
  for (int L = 0; L < 5; ++L) {
    const double q = floor(fma(rr, 0.00390625, 0.5));
    const double d = fma(q, -256.0, rr);
    base[L * 16] = (int8_t)(int)d;
    rr = q;
  }
}

// ---------------------------------------------------------------------------
// X prep: 4 balanced i8 limbs @2^28, packed B-fragment layout
//   XP[tb][cchunk(16)][n(2048)][limb(4)][16 bytes]
// ---------------------------------------------------------------------------
__global__ __launch_bounds__(256) void xprep_kernel(const float* __restrict__ X,
                                                    uint8_t* __restrict__ XP) {
  __shared__ float Xs[64][81];
  const int n0 = blockIdx.x * 64;
  const int tb = blockIdx.y;
  const int tid = (int)threadIdx.x;
  const int c_l = tid >> 2, nc = tid & 3;
  const int n_l = tid & 63, cq = tid >> 6;

  const float* Xp = X + ((size_t)(tb * C_ + c_l)) * N_ + n0 + nc * 16;

  for (int slab = 0; slab < 4; ++slab) {
    __syncthreads();
#pragma unroll
    for (int r = 0; r < 4; ++r) {
      const float4 xv = *(const float4*)(Xp + (size_t)(slab * 64) * N_ + 4 * r);
      Xs[c_l][nc * 16 + 4 * r + 0] = xv.x;
      Xs[c_l][nc * 16 + 4 * r + 1] = xv.y;
      Xs[c_l][nc * 16 + 4 * r + 2] = xv.z;
      Xs[c_l][nc * 16 + 4 * r + 3] = xv.w;
    }
    __syncthreads();
    uint32_t pk[4][4] = {};
#pragma unroll
    for (int s = 0; s < 16; ++s) {
      const float f = Xs[cq * 16 + s][n_l];
      union { double d; unsigned long long u; } cv;
      cv.d = fma((double)f, 0x1p28, 0x1.8p52);  // RNE round; low dword = int32
      int v = (int)(uint32_t)(cv.u & 0xffffffffULL);
      const int d0 = (int)(int8_t)v;  v = (v - d0) >> 8;
      const int d1 = (int)(int8_t)v;  v = (v - d1) >> 8;
      const int d2 = (int)(int8_t)v;
      const int d3 = (v - d2) >> 8;
      const int sh = 8 * (s & 3);
      const int w = s >> 2;
      pk[0][w] |= (uint32_t)(d0 & 255) << sh;
      pk[1][w] |= (uint32_t)(d1 & 255) << sh;
      pk[2][w] |= (uint32_t)(d2 & 255) << sh;
      pk[3][w] |= (uint32_t)(d3 & 255) << sh;
    }
    uint8_t* dst =
        XP + (((size_t)(tb * 16 + slab * 4 + cq)) * (size_t)N_ + n0 + n_l) * 64;
#pragma unroll
    for (int j = 0; j < 4; ++j) {
      const int4 wv = make_int4((int)pk[j][0], (int)pk[j][1], (int)pk[j][2], (int)pk[j][3]);
      *(int4*)(dst + 16 * j) = wv;
    }
  }
}

// ---------------------------------------------------------------------------
// Barrier-free i8 GEMM conv (round-8-proven core). SINGLE pass per stage:
// epilogue stores h compactly (fp32 + i8 residual @2^-27) AND stats partials.
//   QKV=true : XP 4-limb B; 14 MFMAs/mt (i+j>=3); h = sum_a acc_a*2^(8a-44).
//   QKV=false: SbufT binary B; 5 MFMAs/mt; h = sum_i acc_i*2^(8i-40).
// D layout: col=lane&15 (=n), row=4*(lane>>4)+reg [HW-verified m121-128].
// ---------------------------------------------------------------------------
template <bool QKV>
__global__ __launch_bounds__(256) void conv_gemm(
    const int8_t* __restrict__ WP, const uint8_t* __restrict__ BP,
    float* __restrict__ hF, int8_t* __restrict__ hR,
    double* __restrict__ Psum, double* __restrict__ Psq) {
  __shared__ double dsum[4][64];
  __shared__ double dsq[4][64];
  const int n0 = blockIdx.x * 64;
  const int o0 = blockIdx.y * 64;
  const int tb = blockIdx.z;
  const int tid = (int)threadIdx.x;
  const int wv = tid >> 6;
  const int lane = tid & 63;
  const int l15 = lane & 15;
  const int g = lane >> 4;
  const int nn = 16 * wv + l15;

  v4i acc[4][5] = {};

  for (int slab = 0; slab < 4; ++slab) {
    const int cc = slab * 4 + g;
    v4i Bf[4];
    if constexpr (QKV) {
      const uint8_t* bp = BP + (((size_t)(tb * 16 + cc)) * (size_t)N_ + n0 + nn) * 64;
#pragma unroll
      for (int j = 0; j < 4; ++j) Bf[j] = *(const v4i*)(bp + 16 * j);
    } else {
      Bf[0] = *(const v4i*)(BP + ((size_t)(tb * N_ + n0 + nn)) * 256 + slab * 64 + 16 * g);
    }
#pragma unroll
    for (int mt = 0; mt < 4; ++mt) {
      const int8_t* ap = WP + (size_t)cc * 20480 + (size_t)(o0 + 16 * mt + l15) * 80;
      v4i A[5];
#pragma unroll
      for (int i = 0; i < 5; ++i) A[i] = *(const v4i*)(ap + 16 * i);
      if constexpr (QKV) {
        constexpr int PI[14] = {0, 1, 2, 3, 4, 1, 2, 3, 4, 2, 3, 4, 3, 4};
        constexpr int PJ[14] = {3, 3, 3, 3, 3, 2, 2, 2, 2, 1, 1, 1, 0, 0};
#pragma unroll
        for (int p = 0; p < 14; ++p)
          acc[mt][PI[p] + PJ[p] - 3] = __builtin_amdgcn_mfma_i32_16x16x64_i8(
              A[PI[p]], Bf[PJ[p]], acc[mt][PI[p] + PJ[p] - 3], 0, 0, 0);
      } else {
#pragma unroll
        for (int i = 0; i < 5; ++i)
          acc[mt][i] = __builtin_amdgcn_mfma_i32_16x16x64_i8(A[i], Bf[0], acc[mt][i], 0, 0, 0);
      }
    }
  }

  const double scale[5] = {QKV ? 0x1p-44 : 0x1p-40, QKV ? 0x1p-36 : 0x1p-32,
                           QKV ? 0x1p-28 : 0x1p-24, QKV ? 0x1p-20 : 0x1p-16,
                           QKV ? 0x1p-12 : 0x1p-8};

#pragma unroll
  for (int mt = 0; mt < 4; ++mt) {
    double s[4], q[4];
#pragma unroll
    for (int r = 0; r < 4; ++r) {
      double v = 0.0;
#pragma unroll
      for (int a = 0; a < 5; ++a) v = fma(scale[a], (double)acc[mt][a][r], v);
      const int row = 16 * mt + 4 * g + r;
      const size_t idx = ((size_t)(tb * C_ + o0 + row)) * N_ + n0 + nn;
      const float f = (float)v;
      hF[idx] = f;
      int ri = (int)rint((v - (double)f) * 0x1p27);
      ri = ri < -127 ? -127 : (ri > 127 ? 127 : ri);
      hR[idx] = (int8_t)ri;
      s[r] = v;
      q[r] = v * v;
    }
#pragma unroll
    for (int m = 1; m < 16; m <<= 1) {
#pragma unroll
      for (int r = 0; r < 4; ++r) {
        s[r] += __shfl_xor(s[r], m);
        q[r] += __shfl_xor(q[r], m);
      }
    }
    if (l15 < 4) {
      dsum[wv][16 * mt + 4 * g + l15] = s[l15];
      dsq[wv][16 * mt + 4 * g + l15] = q[l15];
    }
  }
  __syncthreads();
  if (tid < 64) {
    const double S = dsum[0][tid] + dsum[1][tid] + dsum[2][tid] + dsum[3][tid];
    const double Q = dsq[0][tid] + dsq[1][tid] + dsq[2][tid] + dsq[3][tid];
    const int slot = tb * 32 + (int)blockIdx.x;
    Psum[(size_t)(o0 + tid) * NSLOT + slot] = S;
    Psq[(size_t)(o0 + tid) * NSLOT + slot] = Q;
  }
}

// ---------------------------------------------------------------------------
// Finalize BN stats: one block per channel, reduce NSLOT partials (fp64).
// ---------------------------------------------------------------------------
__global__ __launch_bounds__(256) void finalize_stats(const double* __restrict__ Psum,
                                                      const double* __restrict__ Psq,
                                                      double* __restrict__ mean,
                                                      double* __restrict__ invstd) {
  const int c = blockIdx.x;
  const int tid = (int)threadIdx.x;
  double s = 0.0, q = 0.0;
  for (int i = tid; i < NSLOT; i += 256) {
    s += Psum[(size_t)c * NSLOT + i];
    q += Psq[(size_t)c * NSLOT + i];
  }
#pragma unroll
  for (int m = 1; m < 64; m <<= 1) {
    s += __shfl_xor(s, m);
    q += __shfl_xor(q, m);
  }
  __shared__ double ls[4], lq[4];
  if ((tid & 63) == 0) {
    ls[tid >> 6] = s;
    lq[tid >> 6] = q;
  }
  __syncthreads();
  if (tid == 0) {
    const double S = ls[0] + ls[1] + ls[2] + ls[3];
    const double Q = lq[0] + lq[1] + lq[2] + lq[3];
    const double m = S / (double)NTOT;
    const double var = Q / (double)NTOT - m * m;
    mean[c] = m;
    invstd[c] = 1.0 / sqrt(var + EPS);
  }
}

// ---------------------------------------------------------------------------
// Spike pass: reconstruct h = f + r*2^-27, BN+spike. 8 elems/thread.
// MODE 0: u8 bytes (Q). MODE 1: bit-packed u8 (K/V). MODE 2: f32 (final out).
// One block covers exactly one (tb,c) row (256 thr * 8 = 2048 = N_).
// ---------------------------------------------------------------------------
template <int MODE>
__global__ __launch_bounds__(256) void spike_pass(
    const float* __restrict__ hF, const int8_t* __restrict__ hR,
    const float* __restrict__ gamma, const float* __restrict__ beta,
    const double* __restrict__ mean, const double* __restrict__ invstd,
    uint8_t* __restrict__ outB, float* __restrict__ outF) {
  const size_t i0 = ((size_t)blockIdx.x * 256 + threadIdx.x) * 8;
  const int c = (int)((i0 >> 11) & 255);
  const double a = (double)gamma[c] * invstd[c];
  const double b = (double)beta[c] - (double)gamma[c] * mean[c] * invstd[c];
  const float4 f0 = *(const float4*)(hF + i0);
  const float4 f1 = *(const float4*)(hF + i0 + 4);
  const uint64_t rw = *(const uint64_t*)(hR + i0);
  const float fs[8] = {f0.x, f0.y, f0.z, f0.w, f1.x, f1.y, f1.z, f1.w};
  int sp[8];
#pragma unroll
  for (int j = 0; j < 8; ++j) {
    const int8_t r8 = (int8_t)((rw >> (8 * j)) & 255);
    const double v = (double)fs[j] + (double)r8 * 0x1p-27;
    sp[j] = (a * v + b >= 1.0) ? 1 : 0;
  }
  if constexpr (MODE == 0) {
    uint64_t w = 0;
#pragma unroll
    for (int j = 0; j < 8; ++j) w |= ((uint64_t)(uint8_t)sp[j]) << (8 * j);
    *(uint64_t*)(outB + i0) = w;
  } else if constexpr (MODE == 1) {
    uint32_t byte = 0;
#pragma unroll
    for (int j = 0; j < 8; ++j) byte |= (uint32_t)sp[j] << j;
    outB[i0 >> 3] = (uint8_t)byte;
  } else {
    *(float4*)(outF + i0) =
        make_float4((float)sp[0], (float)sp[1], (float)sp[2], (float)sp[3]);
    *(float4*)(outF + i0 + 4) =
        make_float4((float)sp[4], (float)sp[5], (float)sp[6], (float)sp[7]);
  }
}

// ---------------------------------------------------------------------------
// Linear attention (exact integer path). K/V arrive BIT-PACKED ([tb][c][N/8]);
// Q as bytes. Output transposed bytes SbufT[tb][n][c] for proj B-fragments.
// ---------------------------------------------------------------------------
__global__ __launch_bounds__(256) void attn_kernel(const uint8_t* __restrict__ SqB,
                                                   const uint8_t* __restrict__ SkBit,
                                                   const uint8_t* __restrict__ SvBit,
                                                   uint8_t* __restrict__ SbufT) {
  __shared__ float kvs[16][17];
  const int tb = (int)blockIdx.x >> 4;
  const int h = (int)blockIdx.x & 15;
  const size_t baseQ = ((size_t)(tb * C_ + h * D_)) * N_;
  const size_t baseB = ((size_t)(tb * C_ + h * D_)) * (N_ / 8);
  const int tid = (int)threadIdx.x;
  {
    const int d = tid >> 4, e = tid & 15;
    const uint32_t* kr = (const uint32_t*)(SkBit + baseB + (size_t)d * (N_ / 8));
    const uint32_t* vr = (const uint32_t*)(SvBit + baseB + (size_t)e * (N_ / 8));
    int cnt = 0;
#pragma unroll
    for (int i = 0; i < N_ / 32; ++i) cnt += __popc(kr[i] & vr[i]);
    kvs[d][e] = (float)cnt;
  }
  __syncthreads();
  for (int rep = 0; rep < 8; ++rep) {
    const int n = rep * 256 + tid;
    float qv[16];
#pragma unroll
    for (int d = 0; d < 16; ++d) qv[d] = (float)SqB[baseQ + (size_t)d * N_ + n];
    uint32_t w[4] = {0, 0, 0, 0};
#pragma unroll
    for (int e = 0; e < 16; ++e) {
      float acc = 0.f;
#pragma unroll
      for (int d = 0; d < 16; ++d) acc += qv[d] * kvs[d][e];
      const uint32_t sp = (0.25f * acc >= 0.5f) ? 1u : 0u;
      w[e >> 2] |= sp << (8 * (e & 3));
    }
    const int4 pw = make_int4((int)w[0], (int)w[1], (int)w[2], (int)w[3]);
    *(int4*)(SbufT + ((size_t)(tb * N_ + n)) * 256 + h * 16) = pw;
  }
}

// ---------------------------------------------------------------------------
// Launcher. ws layout (max 187 MB < proven 192 MB budget):
//   [0,   64M)   XP      (x limbs for Q; REWRITTEN with y limbs after Q-gemm)
//   [64M, 128M)  hF f32
//   [128M,144M)  hR i8
//   [144M,160M)  SqB  (Q spikes, bytes)
//   [160M,162M)  SkBit (K spikes, bit-packed)
//   [162M,164M)  SvBit
//   [164M,180M)  SbufT (attn out, bytes [tb][n][c])
//   [180M,184M)  Psum/Psq
//   [184M,+4K)   mean/invstd
//   [185M,...)   WPA (3x320K), WPB (320K)
// ---------------------------------------------------------------------------
extern "C" void kernel_launch(void* const* d_in, const int* in_sizes, int n_in,
                              void* d_out, int out_size, void* d_ws, size_t ws_size,
                              hipStream_t stream) {
  const float* x   = (const float*)d_in[0];
  const float* y   = (const float*)d_in[1];
  const float* q_w = (const float*)d_in[2];
  const float* q_g = (const float*)d_in[3];
  const float* q_b = (const float*)d_in[4];
  const float* k_w = (const float*)d_in[5];
  const float* k_g = (const float*)d_in[6];
  const float* k_b = (const float*)d_in[7];
  const float* v_w = (const float*)d_in[8];
  const float* v_g = (const float*)d_in[9];
  const float* v_b = (const float*)d_in[10];
  const float* p_w = (const float*)d_in[11];
  const float* p_g = (const float*)d_in[12];
  const float* p_b = (const float*)d_in[13];
  float* out = (float*)d_out;

  char* ws = (char*)d_ws;
  uint8_t* XP    = (uint8_t*)ws;
  float*   hF    = (float*)(ws + (size_t)64 * MB);
  int8_t*  hR    = (int8_t*)(ws + (size_t)128 * MB);
  uint8_t* SqB   = (uint8_t*)(ws + (size_t)144 * MB);
  uint8_t* SkBit = (uint8_t*)(ws + (size_t)160 * MB);
  uint8_t* SvBit = (uint8_t*)(ws + (size_t)162 * MB);
  uint8_t* SbufT = (uint8_t*)(ws + (size_t)164 * MB);
  double*  Psum  = (double*)(ws + (size_t)180 * MB);
  double*  Psq   = Psum + (size_t)C_ * NSLOT;
  double*  mean   = (double*)(ws + (size_t)184 * MB);
  double*  invstd = mean + C_;
  int8_t*  WPA   = (int8_t*)(ws + (size_t)185 * MB);
  int8_t*  WPq   = WPA;
  int8_t*  WPk   = WPA + WPSZ;
  int8_t*  WPv   = WPA + 2 * WPSZ;
  int8_t*  WPB   = WPA + 3 * WPSZ;

  const dim3 gridG(N_ / 64, C_ / 64, TB_);  // 32,4,32
  const dim3 blk(256);
  const int spikeBlocks = (int)((size_t)TB_ * C_ * N_ / (256 * 8));  // 8192

  // --- prep ---
  wprep_kernel<<<dim3(C_, 3), blk, 0, stream>>>(q_w, k_w, v_w, WPA);
  wprep_kernel<<<dim3(C_, 1), blk, 0, stream>>>(p_w, p_w, p_w, WPB);
  xprep_kernel<<<dim3(N_ / 64, TB_), blk, 0, stream>>>(x, XP);
  // --- Q from x ---
  conv_gemm<true><<<gridG, blk, 0, stream>>>(WPq, XP, hF, hR, Psum, Psq);
  finalize_stats<<<C_, blk, 0, stream>>>(Psum, Psq, mean, invstd);
  spike_pass<0><<<spikeBlocks, blk, 0, stream>>>(hF, hR, q_g, q_b, mean, invstd, SqB, nullptr);
  // --- re-extract XP with y (XPx dead after Q gemm) ---
  xprep_kernel<<<dim3(N_ / 64, TB_), blk, 0, stream>>>(y, XP);
  // --- K from y ---
  conv_gemm<true><<<gridG, blk, 0, stream>>>(WPk, XP, hF, hR, Psum, Psq);
  finalize_stats<<<C_, blk, 0, stream>>>(Psum, Psq, mean, invstd);
  spike_pass<1><<<spikeBlocks, blk, 0, stream>>>(hF, hR, k_g, k_b, mean, invstd, SkBit, nullptr);
  // --- V from y ---
  conv_gemm<true><<<gridG, blk, 0, stream>>>(WPv, XP, hF, hR, Psum, Psq);
  finalize_stats<<<C_, blk, 0, stream>>>(Psum, Psq, mean, invstd);
  spike_pass<1><<<spikeBlocks, blk, 0, stream>>>(hF, hR, v_g, v_b, mean, invstd, SvBit, nullptr);
  // --- attention ---
  attn_kernel<<<TB_ * H_, blk, 0, stream>>>(SqB, SkBit, SvBit, SbufT);
  // --- proj ---
  conv_gemm<false><<<gridG, blk, 0, stream>>>(WPB, SbufT, hF, hR, Psum, Psq);
  finalize_stats<<<C_, blk, 0, stream>>>(Psum, Psq, mean, invstd);
  spike_pass<2><<<spikeBlocks, blk, 0, stream>>>(hF, hR, p_g, p_b, mean, invstd, nullptr, out);
}

// Round 10
// 664.164 us; speedup vs baseline: 1.2376x; 1.0196x over previous
//
#include <hip/hip_runtime.h>
#include <stdint.h>
#include <math.h>

// Problem dims
#define T_ 4
#define B_ 8
#define C_ 256
#define N_ 2048
#define TB_ 32          // T_*B_
#define H_ 16
#define D_ 16
#define NTOT 65536      // T_*B_*N_  (BN reduction count per channel)
#define EPS 1e-5
#define NSLOT 1024      // per-channel partial-stat slots = n_blocks(32) * tb(32)
#define WPSZ 327680     // 16 cchunk * 256 o * 5 limb * 16 B
#define MB (1024 * 1024)

typedef int v4i __attribute__((ext_vector_type(4)));

// ---------------------------------------------------------------------------
// W prep: 5 balanced i8 limbs @2^40 in A-fragment layout
//   WP[cchunk(16)][o(256)][limb(5)][16 bytes]
// ---------------------------------------------------------------------------
__global__ __launch_bounds__(256) void wprep_kernel(const float* __restrict__ W0,
                                                    const float* __restrict__ W1,
                                                    const float* __restrict__ W2,
                                                    int8_t* __restrict__ out) {
  const float* Wm = (blockIdx.y == 0) ? W0 : ((blockIdx.y == 1) ? W1 : W2);
  const int o = blockIdx.x;
  const int c = (int)threadIdx.x;
  double rr = rint((double)Wm[o * C_ + c] * 0x1p40);
  int8_t* base = out + (size_t)blockIdx.y * WPSZ + (size_t)(c >> 4) * 20480 +
                 (size_t)o * 80 + (c & 15);
#pragma unroll
  for (int L = 0; L < 5; ++L) {
    const double q = floor(fma(rr, 0.00390625, 0.5));
    const double d = fma(q, -256.0, rr);
    base[L * 16] = (int8_t)(int)d;
    rr = q;
  }
}

// ---------------------------------------------------------------------------
// X prep: 4 balanced i8 limbs @2^28, packed B-fragment layout
//   XP[tb][cchunk(16)][n(2048)][limb(4)][16 bytes]
// ---------------------------------------------------------------------------
__global__ __launch_bounds__(256) void xprep_kernel(const float* __restrict__ X,
                                                    uint8_t* __restrict__ XP) {
  __shared__ float Xs[64][81];
  const int n0 = blockIdx.x * 64;
  const int tb = blockIdx.y;
  const int tid = (int)threadIdx.x;
  const int c_l = tid >> 2, nc = tid & 3;
  const int n_l = tid & 63, cq = tid >> 6;

  const float* Xp = X + ((size_t)(tb * C_ + c_l)) * N_ + n0 + nc * 16;

  for (int slab = 0; slab < 4; ++slab) {
    __syncthreads();
#pragma unroll
    for (int r = 0; r < 4; ++r) {
      const float4 xv = *(const float4*)(Xp + (size_t)(slab * 64) * N_ + 4 * r);
      Xs[c_l][nc * 16 + 4 * r + 0] = xv.x;
      Xs[c_l][nc * 16 + 4 * r + 1] = xv.y;
      Xs[c_l][nc * 16 + 4 * r + 2] = xv.z;
      Xs[c_l][nc * 16 + 4 * r + 3] = xv.w;
    }
    __syncthreads();
    uint32_t pk[4][4] = {};
#pragma unroll
    for (int s = 0; s < 16; ++s) {
      const float f = Xs[cq * 16 + s][n_l];
      union { double d; unsigned long long u; } cv;
      cv.d = fma((double)f, 0x1p28, 0x1.8p52);  // RNE round; low dword = int32
      int v = (int)(uint32_t)(cv.u & 0xffffffffULL);
      const int d0 = (int)(int8_t)v;  v = (v - d0) >> 8;
      const int d1 = (int)(int8_t)v;  v = (v - d1) >> 8;
      const int d2 = (int)(int8_t)v;
      const int d3 = (v - d2) >> 8;
      const int sh = 8 * (s & 3);
      const int w = s >> 2;
      pk[0][w] |= (uint32_t)(d0 & 255) << sh;
      pk[1][w] |= (uint32_t)(d1 & 255) << sh;
      pk[2][w] |= (uint32_t)(d2 & 255) << sh;
      pk[3][w] |= (uint32_t)(d3 & 255) << sh;
    }
    uint8_t* dst =
        XP + (((size_t)(tb * 16 + slab * 4 + cq)) * (size_t)N_ + n0 + n_l) * 64;
#pragma unroll
    for (int j = 0; j < 4; ++j) {
      const int4 wv = make_int4((int)pk[j][0], (int)pk[j][1], (int)pk[j][2], (int)pk[j][3]);
      *(int4*)(dst + 16 * j) = wv;
    }
  }
}

// ---------------------------------------------------------------------------
// i8 GEMM conv, round-9 core + LDS-SHARED A (double-buffered, 1 barrier/slab).
// Each slab's 20 KB A-set (4 cc x 64 o x 5 limbs x 16 B) is staged once per
// block (80 B/thread, coalesced) instead of privately per wave (4x L2 cut).
// Next slab's A is prefetched into registers during the MFMA burst.
//   QKV=true : XP 4-limb B; 14 MFMAs/mt (i+j>=3); h = sum_a acc_a*2^(8a-44).
//   QKV=false: SbufT binary B; 5 MFMAs/mt; h = sum_i acc_i*2^(8i-40).
// Epilogue: h stored as fp32 + i8 residual @2^-27, plus per-channel stats
// partials. D layout: col=lane&15 (=n), row=4*(lane>>4)+reg [m121-128].
// ---------------------------------------------------------------------------
template <bool QKV>
__global__ __launch_bounds__(256) void conv_gemm(
    const int8_t* __restrict__ WP, const uint8_t* __restrict__ BP,
    float* __restrict__ hF, int8_t* __restrict__ hR,
    double* __restrict__ Psum, double* __restrict__ Psq) {
  __shared__ int8_t Alds[2][4][5120];   // [buf][ccLocal][o_l*80 + limb*16]
  __shared__ double dsum[4][64];
  __shared__ double dsq[4][64];
  const int n0 = blockIdx.x * 64;
  const int o0 = blockIdx.y * 64;
  const int tb = blockIdx.z;
  const int tid = (int)threadIdx.x;
  const int wv = tid >> 6;
  const int lane = tid & 63;
  const int l15 = lane & 15;
  const int g = lane >> 4;
  const int nn = 16 * wv + l15;

  // A staging: thread -> (ccLocal, o row); 80 B each, coalesced.
  const int ccL = tid >> 6;
  const int o_l = tid & 63;
  const int8_t* Asrc = WP + (size_t)ccL * 20480 + (size_t)(o0 + o_l) * 80;

  // ---- prologue: stage slab 0's A ----
  {
    v4i t[5];
#pragma unroll
    for (int i = 0; i < 5; ++i) t[i] = *(const v4i*)(Asrc + 16 * i);
#pragma unroll
    for (int i = 0; i < 5; ++i) *(v4i*)&Alds[0][ccL][o_l * 80 + 16 * i] = t[i];
  }
  __syncthreads();

  v4i acc[4][5] = {};

  for (int slab = 0; slab < 4; ++slab) {
    const int buf = slab & 1;
    const int cc = slab * 4 + g;
    // B fragments for this slab (direct global, per-wave distinct)
    v4i Bf[4];
    if constexpr (QKV) {
      const uint8_t* bp = BP + (((size_t)(tb * 16 + cc)) * (size_t)N_ + n0 + nn) * 64;
#pragma unroll
      for (int j = 0; j < 4; ++j) Bf[j] = *(const v4i*)(bp + 16 * j);
    } else {
      Bf[0] = *(const v4i*)(BP + ((size_t)(tb * N_ + n0 + nn)) * 256 + slab * 64 + 16 * g);
    }
    // prefetch next slab's A into registers (latency hides under MFMA)
    v4i pre[5];
    if (slab < 3) {
      const int8_t* ps = Asrc + (size_t)(slab + 1) * 81920;
#pragma unroll
      for (int i = 0; i < 5; ++i) pre[i] = *(const v4i*)(ps + 16 * i);
    }
    // ---- MFMA burst: 4 m-tiles, A from LDS ----
#pragma unroll
    for (int mt = 0; mt < 4; ++mt) {
      v4i A[5];
#pragma unroll
      for (int i = 0; i < 5; ++i)
        A[i] = *(const v4i*)&Alds[buf][g][(16 * mt + l15) * 80 + 16 * i];
      if constexpr (QKV) {
        constexpr int PI[14] = {0, 1, 2, 3, 4, 1, 2, 3, 4, 2, 3, 4, 3, 4};
        constexpr int PJ[14] = {3, 3, 3, 3, 3, 2, 2, 2, 2, 1, 1, 1, 0, 0};
#pragma unroll
        for (int p = 0; p < 14; ++p)
          acc[mt][PI[p] + PJ[p] - 3] = __builtin_amdgcn_mfma_i32_16x16x64_i8(
              A[PI[p]], Bf[PJ[p]], acc[mt][PI[p] + PJ[p] - 3], 0, 0, 0);
      } else {
#pragma unroll
        for (int i = 0; i < 5; ++i)
          acc[mt][i] = __builtin_amdgcn_mfma_i32_16x16x64_i8(A[i], Bf[0], acc[mt][i], 0, 0, 0);
      }
    }
    // ---- write prefetched A into the other buffer; one barrier per slab ----
    if (slab < 3) {
#pragma unroll
      for (int i = 0; i < 5; ++i)
        *(v4i*)&Alds[buf ^ 1][ccL][o_l * 80 + 16 * i] = pre[i];
      __syncthreads();
    }
  }

  const double scale[5] = {QKV ? 0x1p-44 : 0x1p-40, QKV ? 0x1p-36 : 0x1p-32,
                           QKV ? 0x1p-28 : 0x1p-24, QKV ? 0x1p-20 : 0x1p-16,
                           QKV ? 0x1p-12 : 0x1p-8};

#pragma unroll
  for (int mt = 0; mt < 4; ++mt) {
    double s[4], q[4];
#pragma unroll
    for (int r = 0; r < 4; ++r) {
      double v = 0.0;
#pragma unroll
      for (int a = 0; a < 5; ++a) v = fma(scale[a], (double)acc[mt][a][r], v);
      const int row = 16 * mt + 4 * g + r;
      const size_t idx = ((size_t)(tb * C_ + o0 + row)) * N_ + n0 + nn;
      const float f = (float)v;
      hF[idx] = f;
      int ri = (int)rint((v - (double)f) * 0x1p27);
      ri = ri < -127 ? -127 : (ri > 127 ? 127 : ri);
      hR[idx] = (int8_t)ri;
      s[r] = v;
      q[r] = v * v;
    }
#pragma unroll
    for (int m = 1; m < 16; m <<= 1) {
#pragma unroll
      for (int r = 0; r < 4; ++r) {
        s[r] += __shfl_xor(s[r], m);
        q[r] += __shfl_xor(q[r], m);
      }
    }
    if (l15 < 4) {
      dsum[wv][16 * mt + 4 * g + l15] = s[l15];
      dsq[wv][16 * mt + 4 * g + l15] = q[l15];
    }
  }
  __syncthreads();
  if (tid < 64) {
    const double S = dsum[0][tid] + dsum[1][tid] + dsum[2][tid] + dsum[3][tid];
    const double Q = dsq[0][tid] + dsq[1][tid] + dsq[2][tid] + dsq[3][tid];
    const int slot = tb * 32 + (int)blockIdx.x;
    Psum[(size_t)(o0 + tid) * NSLOT + slot] = S;
    Psq[(size_t)(o0 + tid) * NSLOT + slot] = Q;
  }
}

// ---------------------------------------------------------------------------
// Finalize BN stats: one block per channel, reduce NSLOT partials (fp64).
// ---------------------------------------------------------------------------
__global__ __launch_bounds__(256) void finalize_stats(const double* __restrict__ Psum,
                                                      const double* __restrict__ Psq,
                                                      double* __restrict__ mean,
                                                      double* __restrict__ invstd) {
  const int c = blockIdx.x;
  const int tid = (int)threadIdx.x;
  double s = 0.0, q = 0.0;
  for (int i = tid; i < NSLOT; i += 256) {
    s += Psum[(size_t)c * NSLOT + i];
    q += Psq[(size_t)c * NSLOT + i];
  }
#pragma unroll
  for (int m = 1; m < 64; m <<= 1) {
    s += __shfl_xor(s, m);
    q += __shfl_xor(q, m);
  }
  __shared__ double ls[4], lq[4];
  if ((tid & 63) == 0) {
    ls[tid >> 6] = s;
    lq[tid >> 6] = q;
  }
  __syncthreads();
  if (tid == 0) {
    const double S = ls[0] + ls[1] + ls[2] + ls[3];
    const double Q = lq[0] + lq[1] + lq[2] + lq[3];
    const double m = S / (double)NTOT;
    const double var = Q / (double)NTOT - m * m;
    mean[c] = m;
    invstd[c] = 1.0 / sqrt(var + EPS);
  }
}

// ---------------------------------------------------------------------------
// Spike pass: reconstruct h = f + r*2^-27, BN+spike. 8 elems/thread.
// MODE 0: u8 bytes (Q). MODE 1: bit-packed u8 (K/V). MODE 2: f32 (final out).
// ---------------------------------------------------------------------------
template <int MODE>
__global__ __launch_bounds__(256) void spike_pass(
    const float* __restrict__ hF, const int8_t* __restrict__ hR,
    const float* __restrict__ gamma, const float* __restrict__ beta,
    const double* __restrict__ mean, const double* __restrict__ invstd,
    uint8_t* __restrict__ outB, float* __restrict__ outF) {
  const size_t i0 = ((size_t)blockIdx.x * 256 + threadIdx.x) * 8;
  const int c = (int)((i0 >> 11) & 255);
  const double a = (double)gamma[c] * invstd[c];
  const double b = (double)beta[c] - (double)gamma[c] * mean[c] * invstd[c];
  const float4 f0 = *(const float4*)(hF + i0);
  const float4 f1 = *(const float4*)(hF + i0 + 4);
  const uint64_t rw = *(const uint64_t*)(hR + i0);
  const float fs[8] = {f0.x, f0.y, f0.z, f0.w, f1.x, f1.y, f1.z, f1.w};
  int sp[8];
#pragma unroll
  for (int j = 0; j < 8; ++j) {
    const int8_t r8 = (int8_t)((rw >> (8 * j)) & 255);
    const double v = (double)fs[j] + (double)r8 * 0x1p-27;
    sp[j] = (a * v + b >= 1.0) ? 1 : 0;
  }
  if constexpr (MODE == 0) {
    uint64_t w = 0;
#pragma unroll
    for (int j = 0; j < 8; ++j) w |= ((uint64_t)(uint8_t)sp[j]) << (8 * j);
    *(uint64_t*)(outB + i0) = w;
  } else if constexpr (MODE == 1) {
    uint32_t byte = 0;
#pragma unroll
    for (int j = 0; j < 8; ++j) byte |= (uint32_t)sp[j] << j;
    outB[i0 >> 3] = (uint8_t)byte;
  } else {
    *(float4*)(outF + i0) =
        make_float4((float)sp[0], (float)sp[1], (float)sp[2], (float)sp[3]);
    *(float4*)(outF + i0 + 4) =
        make_float4((float)sp[4], (float)sp[5], (float)sp[6], (float)sp[7]);
  }
}

// ---------------------------------------------------------------------------
// Linear attention (exact integer path). K/V bit-packed; Q bytes.
// Output transposed bytes SbufT[tb][n][c] for proj B-fragments.
// ---------------------------------------------------------------------------
__global__ __launch_bounds__(256) void attn_kernel(const uint8_t* __restrict__ SqB,
                                                   const uint8_t* __restrict__ SkBit,
                                                   const uint8_t* __restrict__ SvBit,
                                                   uint8_t* __restrict__ SbufT) {
  __shared__ float kvs[16][17];
  const int tb = (int)blockIdx.x >> 4;
  const int h = (int)blockIdx.x & 15;
  const size_t baseQ = ((size_t)(tb * C_ + h * D_)) * N_;
  const size_t baseB = ((size_t)(tb * C_ + h * D_)) * (N_ / 8);
  const int tid = (int)threadIdx.x;
  {
    const int d = tid >> 4, e = tid & 15;
    const uint32_t* kr = (const uint32_t*)(SkBit + baseB + (size_t)d * (N_ / 8));
    const uint32_t* vr = (const uint32_t*)(SvBit + baseB + (size_t)e * (N_ / 8));
    int cnt = 0;
#pragma unroll
    for (int i = 0; i < N_ / 32; ++i) cnt += __popc(kr[i] & vr[i]);
    kvs[d][e] = (float)cnt;
  }
  __syncthreads();
  for (int rep = 0; rep < 8; ++rep) {
    const int n = rep * 256 + tid;
    float qv[16];
#pragma unroll
    for (int d = 0; d < 16; ++d) qv[d] = (float)SqB[baseQ + (size_t)d * N_ + n];
    uint32_t w[4] = {0, 0, 0, 0};
#pragma unroll
    for (int e = 0; e < 16; ++e) {
      float acc = 0.f;
#pragma unroll
      for (int d = 0; d < 16; ++d) acc += qv[d] * kvs[d][e];
      const uint32_t sp = (0.25f * acc >= 0.5f) ? 1u : 0u;
      w[e >> 2] |= sp << (8 * (e & 3));
    }
    const int4 pw = make_int4((int)w[0], (int)w[1], (int)w[2], (int)w[3]);
    *(int4*)(SbufT + ((size_t)(tb * N_ + n)) * 256 + h * 16) = pw;
  }
}

// ---------------------------------------------------------------------------
// Launcher. ws layout (max 187 MB < proven 192 MB budget):
//   [0,   64M)   XP      (x limbs for Q; REWRITTEN with y limbs after Q-gemm)
//   [64M, 128M)  hF f32
//   [128M,144M)  hR i8
//   [144M,160M)  SqB  (Q spikes, bytes)
//   [160M,162M)  SkBit (K spikes, bit-packed)
//   [162M,164M)  SvBit
//   [164M,180M)  SbufT (attn out, bytes [tb][n][c])
//   [180M,184M)  Psum/Psq
//   [184M,+4K)   mean/invstd
//   [185M,...)   WPA (3x320K), WPB (320K)
// ---------------------------------------------------------------------------
extern "C" void kernel_launch(void* const* d_in, const int* in_sizes, int n_in,
                              void* d_out, int out_size, void* d_ws, size_t ws_size,
                              hipStream_t stream) {
  const float* x   = (const float*)d_in[0];
  const float* y   = (const float*)d_in[1];
  const float* q_w = (const float*)d_in[2];
  const float* q_g = (const float*)d_in[3];
  const float* q_b = (const float*)d_in[4];
  const float* k_w = (const float*)d_in[5];
  const float* k_g = (const float*)d_in[6];
  const float* k_b = (const float*)d_in[7];
  const float* v_w = (const float*)d_in[8];
  const float* v_g = (const float*)d_in[9];
  const float* v_b = (const float*)d_in[10];
  const float* p_w = (const float*)d_in[11];
  const float* p_g = (const float*)d_in[12];
  const float* p_b = (const float*)d_in[13];
  float* out = (float*)d_out;

  char* ws = (char*)d_ws;
  uint8_t* XP    = (uint8_t*)ws;
  float*   hF    = (float*)(ws + (size_t)64 * MB);
  int8_t*  hR    = (int8_t*)(ws + (size_t)128 * MB);
  uint8_t* SqB   = (uint8_t*)(ws + (size_t)144 * MB);
  uint8_t* SkBit = (uint8_t*)(ws + (size_t)160 * MB);
  uint8_t* SvBit = (uint8_t*)(ws + (size_t)162 * MB);
  uint8_t* SbufT = (uint8_t*)(ws + (size_t)164 * MB);
  double*  Psum  = (double*)(ws + (size_t)180 * MB);
  double*  Psq   = Psum + (size_t)C_ * NSLOT;
  double*  mean   = (double*)(ws + (size_t)184 * MB);
  double*  invstd = mean + C_;
  int8_t*  WPA   = (int8_t*)(ws + (size_t)185 * MB);
  int8_t*  WPq   = WPA;
  int8_t*  WPk   = WPA + WPSZ;
  int8_t*  WPv   = WPA + 2 * WPSZ;
  int8_t*  WPB   = WPA + 3 * WPSZ;

  const dim3 gridG(N_ / 64, C_ / 64, TB_);  // 32,4,32
  const dim3 blk(256);
  const int spikeBlocks = (int)((size_t)TB_ * C_ * N_ / (256 * 8));  // 8192

  // --- prep ---
  wprep_kernel<<<dim3(C_, 3), blk, 0, stream>>>(q_w, k_w, v_w, WPA);
  wprep_kernel<<<dim3(C_, 1), blk, 0, stream>>>(p_w, p_w, p_w, WPB);
  xprep_kernel<<<dim3(N_ / 64, TB_), blk, 0, stream>>>(x, XP);
  // --- Q from x ---
  conv_gemm<true><<<gridG, blk, 0, stream>>>(WPq, XP, hF, hR, Psum, Psq);
  finalize_stats<<<C_, blk, 0, stream>>>(Psum, Psq, mean, invstd);
  spike_pass<0><<<spikeBlocks, blk, 0, stream>>>(hF, hR, q_g, q_b, mean, invstd, SqB, nullptr);
  // --- re-extract XP with y (XPx dead after Q gemm) ---
  xprep_kernel<<<dim3(N_ / 64, TB_), blk, 0, stream>>>(y, XP);
  // --- K from y ---
  conv_gemm<true><<<gridG, blk, 0, stream>>>(WPk, XP, hF, hR, Psum, Psq);
  finalize_stats<<<C_, blk, 0, stream>>>(Psum, Psq, mean, invstd);
  spike_pass<1><<<spikeBlocks, blk, 0, stream>>>(hF, hR, k_g, k_b, mean, invstd, SkBit, nullptr);
  // --- V from y ---
  conv_gemm<true><<<gridG, blk, 0, stream>>>(WPv, XP, hF, hR, Psum, Psq);
  finalize_stats<<<C_, blk, 0, stream>>>(Psum, Psq, mean, invstd);
  spike_pass<1><<<spikeBlocks, blk, 0, stream>>>(hF, hR, v_g, v_b, mean, invstd, SvBit, nullptr);
  // --- attention ---
  attn_kernel<<<TB_ * H_, blk, 0, stream>>>(SqB, SkBit, SvBit, SbufT);
  // --- proj ---
  conv_gemm<false><<<gridG, blk, 0, stream>>>(WPB, SbufT, hF, hR, Psum, Psq);
  finalize_stats<<<C_, blk, 0, stream>>>(Psum, Psq, mean, invstd);
  spike_pass<2><<<spikeBlocks, blk, 0, stream>>>(hF, hR, p_g, p_b, mean, invstd, nullptr, out);
}